// Round 1
// baseline (337.754 us; speedup 1.0000x reference)
//
#include <hip/hip_runtime.h>

// One wave (64 lanes) per sample n; one lane per PSF point s (S==64).
// Per-sample setup (Rodrigues rotation, center, half-extent) computed
// redundantly per lane (wave-uniform). Trilinear border-zero sampling of the
// 256^3 volume, Gaussian weight from InvCovScaled quadratic form, then a
// 64-lane shfl_xor butterfly reduction for the weighted mean.

#define VOL_N 256
#define S_PSF 64

__global__ __launch_bounds__(256, 4) void psf_sample_kernel(
    const float* __restrict__ vol,        // [256][256][256] (z,y,x)
    const float* __restrict__ sampleGrid, // [N][3]
    const float* __restrict__ ax,         // [N][6]  (rot|trn)
    const float* __restrict__ bound,      // [N][2][3] (-half|half)
    const float* __restrict__ invcov,     // [3][3]
    const float* __restrict__ xyz_psf,    // [N][64][3]
    float* __restrict__ out,              // [N]
    int N)
{
    const int lane = threadIdx.x & 63;
    const int n = blockIdx.x * (blockDim.x >> 6) + (threadIdx.x >> 6);
    if (n >= N) return;

    // ---- wave-uniform per-sample setup ----
    const float vx = ax[n * 6 + 0], vy = ax[n * 6 + 1], vz = ax[n * 6 + 2];
    const float tx = ax[n * 6 + 3], ty = ax[n * 6 + 4], tz = ax[n * 6 + 5];

    const float theta = sqrtf(vx * vx + vy * vy + vz * vz);
    const float kinv = 1.0f / fmaxf(theta, 1e-12f);
    const float kx = vx * kinv, ky = vy * kinv, kz = vz * kinv;
    const float ct = __cosf(theta), st = __sinf(theta);
    const float oc = 1.0f - ct;

    // Rodrigues: R = I + st*K + oc*K^2
    const float r00 = 1.0f + oc * (-(ky * ky + kz * kz));
    const float r01 = -st * kz + oc * kx * ky;
    const float r02 =  st * ky + oc * kx * kz;
    const float r10 =  st * kz + oc * kx * ky;
    const float r11 = 1.0f + oc * (-(kx * kx + kz * kz));
    const float r12 = -st * kx + oc * ky * kz;
    const float r20 = -st * ky + oc * kx * kz;
    const float r21 =  st * kx + oc * ky * kz;
    const float r22 = 1.0f + oc * (-(kx * kx + ky * ky));

    const float px = sampleGrid[n * 3 + 0] + tx;
    const float py = sampleGrid[n * 3 + 1] + ty;
    const float pz = sampleGrid[n * 3 + 2] + tz;

    const float cx = r00 * px + r01 * py + r02 * pz;
    const float cy = r10 * px + r11 * py + r12 * pz;
    const float cz = r20 * px + r21 * py + r22 * pz;

    const float hx = (bound[n * 6 + 3] - bound[n * 6 + 0]) * 0.5f;
    const float hy = (bound[n * 6 + 4] - bound[n * 6 + 1]) * 0.5f;
    const float hz = (bound[n * 6 + 5] - bound[n * 6 + 2]) * 0.5f;

    const float m00 = invcov[0], m01 = invcov[1], m02 = invcov[2];
    const float m10 = invcov[3], m11 = invcov[4], m12 = invcov[5];
    const float m20 = invcov[6], m21 = invcov[7], m22 = invcov[8];

    // ---- per-lane PSF point ----
    const long long base = ((long long)n * S_PSF + lane) * 3;
    const float ox = xyz_psf[base + 0] * hx;
    const float oy = xyz_psf[base + 1] * hy;
    const float oz = xyz_psf[base + 2] * hz;

    // psf position in voxel coords; fold grid-normalize + denormalize:
    // pix = psf * N/(N-1) - 0.5
    const float scale = (float)VOL_N / (float)(VOL_N - 1);
    const float ix = (cx + ox) * scale - 0.5f;
    const float iy = (cy + oy) * scale - 0.5f;
    const float iz = (cz + oz) * scale - 0.5f;

    const float x0f = floorf(ix), y0f = floorf(iy), z0f = floorf(iz);
    const float fx = ix - x0f, fy = iy - y0f, fz = iz - z0f;
    const int x0 = (int)x0f, y0 = (int)y0f, z0 = (int)z0f;
    const int x1 = x0 + 1, y1 = y0 + 1, z1 = z0 + 1;

    const bool vx0 = (unsigned)x0 < (unsigned)VOL_N;
    const bool vx1 = (unsigned)x1 < (unsigned)VOL_N;
    const bool vy0 = (unsigned)y0 < (unsigned)VOL_N;
    const bool vy1 = (unsigned)y1 < (unsigned)VOL_N;
    const bool vz0 = (unsigned)z0 < (unsigned)VOL_N;
    const bool vz1 = (unsigned)z1 < (unsigned)VOL_N;

    // clamped indices (avoid OOB addresses; weight zeroed when invalid)
    const int xc0 = min(max(x0, 0), VOL_N - 1);
    const int xc1 = min(max(x1, 0), VOL_N - 1);
    const int yc0 = min(max(y0, 0), VOL_N - 1);
    const int yc1 = min(max(y1, 0), VOL_N - 1);
    const int zc0 = min(max(z0, 0), VOL_N - 1);
    const int zc1 = min(max(z1, 0), VOL_N - 1);

    const int zo0 = zc0 * (VOL_N * VOL_N), zo1 = zc1 * (VOL_N * VOL_N);
    const int yo0 = yc0 * VOL_N, yo1 = yc1 * VOL_N;

    // issue all 8 loads up front (let the compiler batch vmcnt)
    const float v000 = vol[zo0 + yo0 + xc0];
    const float v001 = vol[zo0 + yo0 + xc1];
    const float v010 = vol[zo0 + yo1 + xc0];
    const float v011 = vol[zo0 + yo1 + xc1];
    const float v100 = vol[zo1 + yo0 + xc0];
    const float v101 = vol[zo1 + yo0 + xc1];
    const float v110 = vol[zo1 + yo1 + xc0];
    const float v111 = vol[zo1 + yo1 + xc1];

    const float wx0 = 1.0f - fx, wx1 = fx;
    const float wy0 = 1.0f - fy, wy1 = fy;
    const float wz0 = 1.0f - fz, wz1 = fz;

    float acc = 0.0f;
    acc += (vx0 && vy0 && vz0) ? v000 * (wx0 * wy0 * wz0) : 0.0f;
    acc += (vx1 && vy0 && vz0) ? v001 * (wx1 * wy0 * wz0) : 0.0f;
    acc += (vx0 && vy1 && vz0) ? v010 * (wx0 * wy1 * wz0) : 0.0f;
    acc += (vx1 && vy1 && vz0) ? v011 * (wx1 * wy1 * wz0) : 0.0f;
    acc += (vx0 && vy0 && vz1) ? v100 * (wx0 * wy0 * wz1) : 0.0f;
    acc += (vx1 && vy0 && vz1) ? v101 * (wx1 * wy0 * wz1) : 0.0f;
    acc += (vx0 && vy1 && vz1) ? v110 * (wx0 * wy1 * wz1) : 0.0f;
    acc += (vx1 && vy1 && vz1) ? v111 * (wx1 * wy1 * wz1) : 0.0f;

    // Gaussian weight from quadratic form c^T M c (c = bound_psf offset)
    const float qx = m00 * ox + m01 * oy + m02 * oz;
    const float qy = m10 * ox + m11 * oy + m12 * oz;
    const float qz = m20 * ox + m21 * oy + m22 * oz;
    const float q = ox * qx + oy * qy + oz * qz;
    const float w = __expf(-0.5f * q);

    float num = acc * w;
    float den = w;
    #pragma unroll
    for (int m = 32; m >= 1; m >>= 1) {
        num += __shfl_xor(num, m, 64);
        den += __shfl_xor(den, m, 64);
    }
    if (lane == 0) out[n] = num / den;
}

extern "C" void kernel_launch(void* const* d_in, const int* in_sizes, int n_in,
                              void* d_out, int out_size, void* d_ws, size_t ws_size,
                              hipStream_t stream) {
    const float* x        = (const float*)d_in[0];
    const float* sg       = (const float*)d_in[1];
    const float* ax       = (const float*)d_in[2];
    const float* bound    = (const float*)d_in[3];
    const float* invcov   = (const float*)d_in[4];
    const float* xyz_psf  = (const float*)d_in[5];
    float* out            = (float*)d_out;

    const int N = in_sizes[1] / 3;           // sampleGrid is [N][3]
    const int waves_per_block = 4;           // 256 threads
    dim3 block(256);
    dim3 grid((N + waves_per_block - 1) / waves_per_block);
    psf_sample_kernel<<<grid, block, 0, stream>>>(x, sg, ax, bound, invcov,
                                                  xyz_psf, out, N);
}

// Round 2
// 327.910 us; speedup vs baseline: 1.0300x; 1.0300x over previous
//
#include <hip/hip_runtime.h>

// One wave (64 lanes) per sample n; one lane per PSF point s (S==64).
// Round 2: spatial sort. Samples are bucketed into 4096 Morton-ordered 16^3
// voxel cells by sampleGrid position (hist -> scan -> scatter into d_ws),
// and the main kernel walks samples in sorted order with an XCD-contiguous
// block swizzle, so co-resident waves share the same small volume region
// (gathers become L1/L2 hits instead of HBM misses).

#define VOL_N 256
#define S_PSF 64
#define NBUCKET 4096   // 16x16x16 cells of 16^3 voxels

// ---- workspace layout (ints) ----
// [0, 4096)              histogram
// [4096, 8192)           bucket offsets (exclusive scan; consumed by scatter)
// [8192, 8192+N)         permutation: sorted position -> sample index

__device__ __forceinline__ int bucket_of(const float* __restrict__ sg, int n) {
    int cx = min(max((int)sg[n * 3 + 0], 0), VOL_N - 1) >> 4;
    int cy = min(max((int)sg[n * 3 + 1], 0), VOL_N - 1) >> 4;
    int cz = min(max((int)sg[n * 3 + 2], 0), VOL_N - 1) >> 4;
    int m = 0;
    #pragma unroll
    for (int b = 0; b < 4; b++) {
        m |= (((cx >> b) & 1) << (3 * b))
           | (((cy >> b) & 1) << (3 * b + 1))
           | (((cz >> b) & 1) << (3 * b + 2));
    }
    return m;
}

__global__ void zero_hist_kernel(int* __restrict__ ws) {
    int i = blockIdx.x * blockDim.x + threadIdx.x;
    if (i < NBUCKET) ws[i] = 0;
}

__global__ void hist_kernel(const float* __restrict__ sg, int* __restrict__ ws, int N) {
    int n = blockIdx.x * blockDim.x + threadIdx.x;
    if (n >= N) return;
    atomicAdd(&ws[bucket_of(sg, n)], 1);
}

__global__ __launch_bounds__(1024) void scan_kernel(int* __restrict__ ws) {
    // exclusive prefix sum of ws[0..4096) -> ws[4096..8192); 1 block, 1024 thr
    __shared__ int tmp[1024];
    const int t = threadIdx.x;
    int h0 = ws[t * 4 + 0], h1 = ws[t * 4 + 1], h2 = ws[t * 4 + 2], h3 = ws[t * 4 + 3];
    int s = h0 + h1 + h2 + h3;
    tmp[t] = s;
    __syncthreads();
    for (int off = 1; off < 1024; off <<= 1) {
        int v = (t >= off) ? tmp[t - off] : 0;
        __syncthreads();
        tmp[t] += v;
        __syncthreads();
    }
    int excl = tmp[t] - s;  // sum of all previous threads' totals
    ws[NBUCKET + t * 4 + 0] = excl;
    ws[NBUCKET + t * 4 + 1] = excl + h0;
    ws[NBUCKET + t * 4 + 2] = excl + h0 + h1;
    ws[NBUCKET + t * 4 + 3] = excl + h0 + h1 + h2;
}

__global__ void scatter_kernel(const float* __restrict__ sg, int* __restrict__ ws, int N) {
    int n = blockIdx.x * blockDim.x + threadIdx.x;
    if (n >= N) return;
    int b = bucket_of(sg, n);
    int pos = atomicAdd(&ws[NBUCKET + b], 1);
    ws[2 * NBUCKET + pos] = n;
}

__global__ __launch_bounds__(256, 4) void psf_sample_kernel(
    const float* __restrict__ vol,        // [256][256][256] (z,y,x)
    const float* __restrict__ sampleGrid, // [N][3]
    const float* __restrict__ ax,         // [N][6]  (rot|trn)
    const float* __restrict__ bound,      // [N][2][3] (-half|half)
    const float* __restrict__ invcov,     // [3][3]
    const float* __restrict__ xyz_psf,    // [N][64][3]
    const int* __restrict__ perm,         // sorted pos -> n (or null)
    float* __restrict__ out,              // [N]
    int N)
{
    const int lane = threadIdx.x & 63;

    // XCD-contiguous swizzle: default round-robin sends consecutive blocks to
    // different XCDs; remap so each XCD gets a contiguous sorted range.
    int bid = blockIdx.x;
    const int nb = gridDim.x;
    if ((nb & 7) == 0) bid = (bid & 7) * (nb >> 3) + (bid >> 3);

    const int i = bid * (blockDim.x >> 6) + (threadIdx.x >> 6);
    if (i >= N) return;
    const int n = perm ? perm[i] : i;

    // ---- wave-uniform per-sample setup ----
    const float vx = ax[n * 6 + 0], vy = ax[n * 6 + 1], vz = ax[n * 6 + 2];
    const float tx = ax[n * 6 + 3], ty = ax[n * 6 + 4], tz = ax[n * 6 + 5];

    const float theta = sqrtf(vx * vx + vy * vy + vz * vz);
    const float kinv = 1.0f / fmaxf(theta, 1e-12f);
    const float kx = vx * kinv, ky = vy * kinv, kz = vz * kinv;
    const float ct = __cosf(theta), st = __sinf(theta);
    const float oc = 1.0f - ct;

    const float r00 = 1.0f + oc * (-(ky * ky + kz * kz));
    const float r01 = -st * kz + oc * kx * ky;
    const float r02 =  st * ky + oc * kx * kz;
    const float r10 =  st * kz + oc * kx * ky;
    const float r11 = 1.0f + oc * (-(kx * kx + kz * kz));
    const float r12 = -st * kx + oc * ky * kz;
    const float r20 = -st * ky + oc * kx * kz;
    const float r21 =  st * kx + oc * ky * kz;
    const float r22 = 1.0f + oc * (-(kx * kx + ky * ky));

    const float px = sampleGrid[n * 3 + 0] + tx;
    const float py = sampleGrid[n * 3 + 1] + ty;
    const float pz = sampleGrid[n * 3 + 2] + tz;

    const float cx = r00 * px + r01 * py + r02 * pz;
    const float cy = r10 * px + r11 * py + r12 * pz;
    const float cz = r20 * px + r21 * py + r22 * pz;

    const float hx = (bound[n * 6 + 3] - bound[n * 6 + 0]) * 0.5f;
    const float hy = (bound[n * 6 + 4] - bound[n * 6 + 1]) * 0.5f;
    const float hz = (bound[n * 6 + 5] - bound[n * 6 + 2]) * 0.5f;

    const float m00 = invcov[0], m01 = invcov[1], m02 = invcov[2];
    const float m10 = invcov[3], m11 = invcov[4], m12 = invcov[5];
    const float m20 = invcov[6], m21 = invcov[7], m22 = invcov[8];

    // ---- per-lane PSF point ----
    const long long base = ((long long)n * S_PSF + lane) * 3;
    const float ox = xyz_psf[base + 0] * hx;
    const float oy = xyz_psf[base + 1] * hy;
    const float oz = xyz_psf[base + 2] * hz;

    const float scale = (float)VOL_N / (float)(VOL_N - 1);
    const float ix = (cx + ox) * scale - 0.5f;
    const float iy = (cy + oy) * scale - 0.5f;
    const float iz = (cz + oz) * scale - 0.5f;

    const float x0f = floorf(ix), y0f = floorf(iy), z0f = floorf(iz);
    const float fx = ix - x0f, fy = iy - y0f, fz = iz - z0f;
    const int x0 = (int)x0f, y0 = (int)y0f, z0 = (int)z0f;
    const int x1 = x0 + 1, y1 = y0 + 1, z1 = z0 + 1;

    const bool vx0 = (unsigned)x0 < (unsigned)VOL_N;
    const bool vx1 = (unsigned)x1 < (unsigned)VOL_N;
    const bool vy0 = (unsigned)y0 < (unsigned)VOL_N;
    const bool vy1 = (unsigned)y1 < (unsigned)VOL_N;
    const bool vz0 = (unsigned)z0 < (unsigned)VOL_N;
    const bool vz1 = (unsigned)z1 < (unsigned)VOL_N;

    const int xc0 = min(max(x0, 0), VOL_N - 1);
    const int xc1 = min(max(x1, 0), VOL_N - 1);
    const int yc0 = min(max(y0, 0), VOL_N - 1);
    const int yc1 = min(max(y1, 0), VOL_N - 1);
    const int zc0 = min(max(z0, 0), VOL_N - 1);
    const int zc1 = min(max(z1, 0), VOL_N - 1);

    const int zo0 = zc0 * (VOL_N * VOL_N), zo1 = zc1 * (VOL_N * VOL_N);
    const int yo0 = yc0 * VOL_N, yo1 = yc1 * VOL_N;

    const float v000 = vol[zo0 + yo0 + xc0];
    const float v001 = vol[zo0 + yo0 + xc1];
    const float v010 = vol[zo0 + yo1 + xc0];
    const float v011 = vol[zo0 + yo1 + xc1];
    const float v100 = vol[zo1 + yo0 + xc0];
    const float v101 = vol[zo1 + yo0 + xc1];
    const float v110 = vol[zo1 + yo1 + xc0];
    const float v111 = vol[zo1 + yo1 + xc1];

    const float wx0 = 1.0f - fx, wx1 = fx;
    const float wy0 = 1.0f - fy, wy1 = fy;
    const float wz0 = 1.0f - fz, wz1 = fz;

    float acc = 0.0f;
    acc += (vx0 && vy0 && vz0) ? v000 * (wx0 * wy0 * wz0) : 0.0f;
    acc += (vx1 && vy0 && vz0) ? v001 * (wx1 * wy0 * wz0) : 0.0f;
    acc += (vx0 && vy1 && vz0) ? v010 * (wx0 * wy1 * wz0) : 0.0f;
    acc += (vx1 && vy1 && vz0) ? v011 * (wx1 * wy1 * wz0) : 0.0f;
    acc += (vx0 && vy0 && vz1) ? v100 * (wx0 * wy0 * wz1) : 0.0f;
    acc += (vx1 && vy0 && vz1) ? v101 * (wx1 * wy0 * wz1) : 0.0f;
    acc += (vx0 && vy1 && vz1) ? v110 * (wx0 * wy1 * wz1) : 0.0f;
    acc += (vx1 && vy1 && vz1) ? v111 * (wx1 * wy1 * wz1) : 0.0f;

    const float qx = m00 * ox + m01 * oy + m02 * oz;
    const float qy = m10 * ox + m11 * oy + m12 * oz;
    const float qz = m20 * ox + m21 * oy + m22 * oz;
    const float q = ox * qx + oy * qy + oz * qz;
    const float w = __expf(-0.5f * q);

    float num = acc * w;
    float den = w;
    #pragma unroll
    for (int m = 32; m >= 1; m >>= 1) {
        num += __shfl_xor(num, m, 64);
        den += __shfl_xor(den, m, 64);
    }
    if (lane == 0) out[n] = num / den;
}

extern "C" void kernel_launch(void* const* d_in, const int* in_sizes, int n_in,
                              void* d_out, int out_size, void* d_ws, size_t ws_size,
                              hipStream_t stream) {
    const float* x        = (const float*)d_in[0];
    const float* sg       = (const float*)d_in[1];
    const float* ax       = (const float*)d_in[2];
    const float* bound    = (const float*)d_in[3];
    const float* invcov   = (const float*)d_in[4];
    const float* xyz_psf  = (const float*)d_in[5];
    float* out            = (float*)d_out;

    const int N = in_sizes[1] / 3;           // sampleGrid is [N][3]
    const size_t ws_needed = (size_t)(2 * NBUCKET + N) * sizeof(int);

    int* perm = nullptr;
    if (ws_size >= ws_needed) {
        int* ws = (int*)d_ws;
        zero_hist_kernel<<<(NBUCKET + 255) / 256, 256, 0, stream>>>(ws);
        hist_kernel<<<(N + 255) / 256, 256, 0, stream>>>(sg, ws, N);
        scan_kernel<<<1, 1024, 0, stream>>>(ws);
        scatter_kernel<<<(N + 255) / 256, 256, 0, stream>>>(sg, ws, N);
        perm = ws + 2 * NBUCKET;
    }

    const int waves_per_block = 4;           // 256 threads
    dim3 block(256);
    dim3 grid((N + waves_per_block - 1) / waves_per_block);
    psf_sample_kernel<<<grid, block, 0, stream>>>(x, sg, ax, bound, invcov,
                                                  xyz_psf, perm, out, N);
}